// Round 1
// baseline (566.677 us; speedup 1.0000x reference)
//
#include <hip/hip_runtime.h>
#include <stdint.h>

#define NTYPES 8
#define OUT_CH 128
#define BM 128
#define BK 32
#define THREADS 256

struct TypeParams {
  const float* x;
  const float* W;
  const float* b;
  float* out;
  int N;
  int C;
  int blk_start;
  unsigned k0, k1;
};

struct KParams {
  TypeParams t[NTYPES];
};

// Exact JAX threefry2x32 (20 rounds, rotations {13,15,26,6}/{17,29,16,24}).
__host__ __device__ __forceinline__ void tf2x32(unsigned k0, unsigned k1,
                                                unsigned c0, unsigned c1,
                                                unsigned& o0, unsigned& o1) {
  unsigned k2 = k0 ^ k1 ^ 0x1BD11BDAu;
  unsigned x0 = c0 + k0;
  unsigned x1 = c1 + k1;
#define TFR(r) { x0 += x1; x1 = (x1 << (r)) | (x1 >> (32 - (r))); x1 ^= x0; }
  TFR(13) TFR(15) TFR(26) TFR(6)
  x0 += k1; x1 += k2 + 1u;
  TFR(17) TFR(29) TFR(16) TFR(24)
  x0 += k2; x1 += k0 + 2u;
  TFR(13) TFR(15) TFR(26) TFR(6)
  x0 += k0; x1 += k1 + 3u;
  TFR(17) TFR(29) TFR(16) TFR(24)
  x0 += k1; x1 += k2 + 4u;
  TFR(13) TFR(15) TFR(26) TFR(6)
  x0 += k2; x1 += k0 + 5u;
#undef TFR
  o0 = x0; o1 = x1;
}

// jax_threefry_partitionable=True path (modern JAX default):
// bits for flat index j = o0 ^ o1 of threefry(key, hi=0, lo=j).
// keep-mask: uniform(bits) < 0.8f  <=>  (bits >> 9) <= 0x666666.
__device__ __forceinline__ bool keep_mask_part(unsigned k0, unsigned k1, unsigned idx) {
  unsigned o0, o1;
  tf2x32(k0, k1, 0u, idx, o0, o1);
  unsigned bits = o0 ^ o1;
  return (bits >> 9) <= 0x666666u;
}

// Legacy (non-partitionable) path, kept for a quick flip if validation fails:
// iota split in halves; j<half: out0 of (j, j+half); else out1 of (j-half, j).
__device__ __forceinline__ bool keep_mask_orig(unsigned k0, unsigned k1,
                                               unsigned idx, unsigned size) {
  unsigned half = size >> 1;
  unsigned o0, o1;
  if (idx < half) {
    tf2x32(k0, k1, idx, idx + half, o0, o1);
    return (o0 >> 9) <= 0x666666u;
  } else {
    tf2x32(k0, k1, idx - half, idx, o0, o1);
    return (o1 >> 9) <= 0x666666u;
  }
}

__global__ __launch_bounds__(THREADS)
void hetero_linear_dropout(KParams P) {
  __shared__ float As[BK][BM];      // x tile, k-major: As[kk][row]
  __shared__ float Ws[BK][OUT_CH];  // W tile, k-major: Ws[kk][outch]

  const int bid = blockIdx.x;
  int t = 0;
#pragma unroll
  for (int i = 1; i < NTYPES; ++i) t += (bid >= P.t[i].blk_start) ? 1 : 0;

  const float* __restrict__ xp = P.t[t].x;
  const float* __restrict__ Wp = P.t[t].W;
  const float* __restrict__ bp = P.t[t].b;
  float* __restrict__ op = P.t[t].out;
  const int N = P.t[t].N;
  const int C = P.t[t].C;
  const unsigned fk0 = P.t[t].k0, fk1 = P.t[t].k1;
  const int row0 = (bid - P.t[t].blk_start) * BM;

  const int tid = threadIdx.x;
  const int ty = tid >> 4;          // 0..15
  const int tx = tid & 15;          // 0..15
  const int ty8 = ty * 8, tx8 = tx * 8;

  // staging assignment: each thread stages 16 floats of one x-row and 16 of one W-row
  const int srow = tid >> 1;        // 0..127
  const int skk  = (tid & 1) * 16;  // 0 or 16

  float acc[8][8];
#pragma unroll
  for (int i = 0; i < 8; ++i)
#pragma unroll
    for (int j = 0; j < 8; ++j) acc[i][j] = 0.f;

  int arow = row0 + srow;
  if (arow >= N) arow = N - 1;                       // clamp for partial last tile
  const float* xrow = xp + (size_t)arow * C + skk;
  const float* wrow = Wp + (size_t)srow * C + skk;   // srow == out-channel

  const int ksteps = C / BK;                         // all C are multiples of 32
  for (int ks = 0; ks < ksteps; ++ks) {
    const float4* xs = reinterpret_cast<const float4*>(xrow + ks * BK);
    const float4* ws = reinterpret_cast<const float4*>(wrow + ks * BK);
    float4 xa = xs[0], xb = xs[1], xc = xs[2], xd = xs[3];
    float4 wa = ws[0], wb = ws[1], wc = ws[2], wd = ws[3];
    __syncthreads();  // previous compute done before overwriting LDS
    {
      float xv[16] = {xa.x,xa.y,xa.z,xa.w, xb.x,xb.y,xb.z,xb.w,
                      xc.x,xc.y,xc.z,xc.w, xd.x,xd.y,xd.z,xd.w};
      float wv[16] = {wa.x,wa.y,wa.z,wa.w, wb.x,wb.y,wb.z,wb.w,
                      wc.x,wc.y,wc.z,wc.w, wd.x,wd.y,wd.z,wd.w};
#pragma unroll
      for (int q = 0; q < 16; ++q) {
        As[skk + q][srow] = xv[q];   // bank = srow%32, 2 lanes/bank -> free
        Ws[skk + q][srow] = wv[q];
      }
    }
    __syncthreads();
#pragma unroll
    for (int kk = 0; kk < BK; ++kk) {
      float4 a0 = *reinterpret_cast<const float4*>(&As[kk][ty8]);
      float4 a1 = *reinterpret_cast<const float4*>(&As[kk][ty8 + 4]);
      float4 b0 = *reinterpret_cast<const float4*>(&Ws[kk][tx8]);
      float4 b1 = *reinterpret_cast<const float4*>(&Ws[kk][tx8 + 4]);
      float av[8] = {a0.x,a0.y,a0.z,a0.w, a1.x,a1.y,a1.z,a1.w};
      float bv[8] = {b0.x,b0.y,b0.z,b0.w, b1.x,b1.y,b1.z,b1.w};
#pragma unroll
      for (int i = 0; i < 8; ++i)
#pragma unroll
        for (int j = 0; j < 8; ++j)
          acc[i][j] = fmaf(av[i], bv[j], acc[i][j]);
    }
  }

  // epilogue: bias + exact-threefry inverted dropout
  float4 bv0 = *reinterpret_cast<const float4*>(bp + tx8);
  float4 bv1 = *reinterpret_cast<const float4*>(bp + tx8 + 4);
  float bias[8] = {bv0.x,bv0.y,bv0.z,bv0.w, bv1.x,bv1.y,bv1.z,bv1.w};

#pragma unroll
  for (int i = 0; i < 8; ++i) {
    const int r = row0 + ty8 + i;
    if (r < N) {
      float o[8];
#pragma unroll
      for (int j = 0; j < 8; ++j) {
        float y = acc[i][j] + bias[j];
        unsigned idx = (unsigned)r * 128u + (unsigned)(tx8 + j);
        y = keep_mask_part(fk0, fk1, idx) ? y * 1.25f : 0.0f;
        o[j] = y;
      }
      float4* dst = reinterpret_cast<float4*>(op + (size_t)r * 128 + tx8);
      dst[0] = make_float4(o[0], o[1], o[2], o[3]);
      dst[1] = make_float4(o[4], o[5], o[6], o[7]);
    }
  }
}

extern "C" void kernel_launch(void* const* d_in, const int* in_sizes, int n_in,
                              void* d_out, int out_size, void* d_ws, size_t ws_size,
                              hipStream_t stream) {
  static const int NS[NTYPES] = {100000, 75000, 62500, 50000, 37500, 30000, 25000, 20000};
  static const int CS[NTYPES] = {128, 256, 64, 128, 192, 96, 160, 128};

  KParams P;
  int blk = 0;
  size_t ooff = 0;
  for (int t = 0; t < NTYPES; ++t) {
    P.t[t].x = (const float*)d_in[3 * t + 0];
    P.t[t].W = (const float*)d_in[3 * t + 1];
    P.t[t].b = (const float*)d_in[3 * t + 2];
    P.t[t].out = (float*)d_out + ooff;
    P.t[t].N = NS[t];
    P.t[t].C = CS[t];
    P.t[t].blk_start = blk;
    unsigned o0, o1;
    tf2x32(0u, 42u, 0u, (unsigned)t, o0, o1);  // fold_in(key(42), t)
    P.t[t].k0 = o0;
    P.t[t].k1 = o1;
    blk += (NS[t] + BM - 1) / BM;
    ooff += (size_t)NS[t] * OUT_CH;
  }

  hipLaunchKernelGGL(hetero_linear_dropout, dim3(blk), dim3(THREADS), 0, stream, P);
}

// Round 3
// 451.746 us; speedup vs baseline: 1.2544x; 1.2544x over previous
//
#include <hip/hip_runtime.h>
#include <hip/hip_bf16.h>
#include <stdint.h>

#define NTYPES 8
#define OUT_CH 128
#define BM 128
#define BK 32
#define THREADS 256

typedef __bf16 bf16x8 __attribute__((ext_vector_type(8)));
typedef float f32x4 __attribute__((ext_vector_type(4)));

struct TypeParams {
  const float* x;
  const float* W;
  const float* b;
  float* out;
  int N;
  int C;
  int blk_start;
  unsigned k0, k1;
};
struct KParams {
  TypeParams t[NTYPES];
};

// Exact JAX threefry2x32 (20 rounds, rotations {13,15,26,6}/{17,29,16,24}).
__host__ __device__ __forceinline__ void tf2x32(unsigned k0, unsigned k1,
                                                unsigned c0, unsigned c1,
                                                unsigned& o0, unsigned& o1) {
  unsigned k2 = k0 ^ k1 ^ 0x1BD11BDAu;
  unsigned x0 = c0 + k0;
  unsigned x1 = c1 + k1;
#define TFR(r) { x0 += x1; x1 = (x1 << (r)) | (x1 >> (32 - (r))); x1 ^= x0; }
  TFR(13) TFR(15) TFR(26) TFR(6)
  x0 += k1; x1 += k2 + 1u;
  TFR(17) TFR(29) TFR(16) TFR(24)
  x0 += k2; x1 += k0 + 2u;
  TFR(13) TFR(15) TFR(26) TFR(6)
  x0 += k0; x1 += k1 + 3u;
  TFR(17) TFR(29) TFR(16) TFR(24)
  x0 += k1; x1 += k2 + 4u;
  TFR(13) TFR(15) TFR(26) TFR(6)
  x0 += k2; x1 += k0 + 5u;
#undef TFR
  o0 = x0; o1 = x1;
}

// bf16 round-to-nearest-even (finite inputs)
__device__ __forceinline__ unsigned short bf_rn(float f) {
  unsigned u = __float_as_uint(f);
  return (unsigned short)((u + 0x7FFFu + ((u >> 16) & 1u)) >> 16);
}

// split pair (a,b) into packed-bf16 hi word and lo word
__device__ __forceinline__ void cvt_hi_lo(float a, float b, unsigned& hi, unsigned& lo) {
  unsigned short ha = bf_rn(a), hb = bf_rn(b);
  float fa = __uint_as_float((unsigned)ha << 16);
  float fb = __uint_as_float((unsigned)hb << 16);
  unsigned short la = bf_rn(a - fa), lb = bf_rn(b - fb);
  hi = (unsigned)ha | ((unsigned)hb << 16);
  lo = (unsigned)la | ((unsigned)lb << 16);
}

// swizzled byte offset within an 8KB plane: row in [0,128), kbyte in [0,64)
__device__ __forceinline__ unsigned swz(int row, int kbyte) {
  return (unsigned)(row * 64 + kbyte) ^ (unsigned)((row & 7) << 4);
}

__global__ __launch_bounds__(THREADS, 3)
void hetero_mfma(KParams P) {
  __shared__ __align__(16) unsigned short XhS[BM * BK];
  __shared__ __align__(16) unsigned short XlS[BM * BK];
  __shared__ __align__(16) unsigned short WhS[OUT_CH * BK];
  __shared__ __align__(16) unsigned short WlS[OUT_CH * BK];
  char* XhB = (char*)XhS;
  char* XlB = (char*)XlS;
  char* WhB = (char*)WhS;
  char* WlB = (char*)WlS;

  const int bid = blockIdx.x;
  int t = 0;
#pragma unroll
  for (int i = 1; i < NTYPES; ++i) t += (bid >= P.t[i].blk_start) ? 1 : 0;

  const float* __restrict__ xp = P.t[t].x;
  const float* __restrict__ Wp = P.t[t].W;
  const float* __restrict__ bp = P.t[t].b;
  float* __restrict__ op = P.t[t].out;
  const int N = P.t[t].N;
  const int C = P.t[t].C;
  const unsigned fk0 = P.t[t].k0, fk1 = P.t[t].k1;
  const int row0 = (bid - P.t[t].blk_start) * BM;

  const int tid = threadIdx.x;
  const int wv = tid >> 6;       // wave 0..3 -> rows [wv*32, wv*32+32)
  const int lane = tid & 63;
  const int lx = lane & 15;
  const int lq = lane >> 4;      // k-group / row-group

  // staging assignment: thread stages half a row of x and of W
  const int srow = tid >> 1;          // 0..127
  const int skk = (tid & 1) * 16;     // element offset 0 or 16

  int arow = row0 + srow;
  if (arow >= N) arow = N - 1;

  // ---- Threefry keep-mask for this lane's 64 output elements ----
  unsigned long long keep64 = 0ULL;
  {
    unsigned ridx_base = (unsigned)(row0 + wv * 32 + lq * 4) * 128u + (unsigned)lx;
#pragma unroll 1
    for (int s = 0; s < 8; ++s) {
      unsigned row_off = (unsigned)(((s >> 2) * 16) + (s & 3));
      unsigned ridx = ridx_base + row_off * 128u;
      unsigned bits8 = 0u;
#pragma unroll
      for (int nt = 0; nt < 8; ++nt) {
        unsigned o0, o1;
        tf2x32(fk0, fk1, 0u, ridx + (unsigned)nt * 16u, o0, o1);
        bits8 |= (unsigned)(((o0 ^ o1) >> 9) <= 0x666666u) << nt;
      }
      keep64 |= (unsigned long long)bits8 << (s * 8);
    }
  }

  // ---- fragment LDS byte offsets (constant across K-steps) ----
  unsigned aOff[2], bOff[8];
#pragma unroll
  for (int mt = 0; mt < 2; ++mt) aOff[mt] = swz(wv * 32 + mt * 16 + lx, lq * 16);
#pragma unroll
  for (int nt = 0; nt < 8; ++nt) bOff[nt] = swz(nt * 16 + lx, lq * 16);

  // staging LDS byte offsets
  const unsigned st0 = swz(srow, skk * 2);
  const unsigned st1 = swz(srow, skk * 2 + 16);

  f32x4 acc[2][8];
#pragma unroll
  for (int mt = 0; mt < 2; ++mt)
#pragma unroll
    for (int nt = 0; nt < 8; ++nt) acc[mt][nt] = (f32x4){0.f, 0.f, 0.f, 0.f};

  const float* xrow = xp + (size_t)arow * C + skk;
  const float* wrow = Wp + (size_t)srow * C + skk;
  const int ksteps = C / BK;

  for (int ks = 0; ks < ksteps; ++ks) {
    // global loads (16 fp32 of x, 16 fp32 of W)
    const float4* xs4 = reinterpret_cast<const float4*>(xrow + ks * BK);
    const float4* ws4 = reinterpret_cast<const float4*>(wrow + ks * BK);
    float4 xa = xs4[0], xb = xs4[1], xc = xs4[2], xd = xs4[3];
    float4 wa = ws4[0], wb = ws4[1], wc = ws4[2], wd = ws4[3];

    // convert to packed bf16 hi/lo (pairs)
    unsigned xh[8], xl[8], wh[8], wl[8];
    cvt_hi_lo(xa.x, xa.y, xh[0], xl[0]);
    cvt_hi_lo(xa.z, xa.w, xh[1], xl[1]);
    cvt_hi_lo(xb.x, xb.y, xh[2], xl[2]);
    cvt_hi_lo(xb.z, xb.w, xh[3], xl[3]);
    cvt_hi_lo(xc.x, xc.y, xh[4], xl[4]);
    cvt_hi_lo(xc.z, xc.w, xh[5], xl[5]);
    cvt_hi_lo(xd.x, xd.y, xh[6], xl[6]);
    cvt_hi_lo(xd.z, xd.w, xh[7], xl[7]);
    cvt_hi_lo(wa.x, wa.y, wh[0], wl[0]);
    cvt_hi_lo(wa.z, wa.w, wh[1], wl[1]);
    cvt_hi_lo(wb.x, wb.y, wh[2], wl[2]);
    cvt_hi_lo(wb.z, wb.w, wh[3], wl[3]);
    cvt_hi_lo(wc.x, wc.y, wh[4], wl[4]);
    cvt_hi_lo(wc.z, wc.w, wh[5], wl[5]);
    cvt_hi_lo(wd.x, wd.y, wh[6], wl[6]);
    cvt_hi_lo(wd.z, wd.w, wh[7], wl[7]);

    __syncthreads();  // previous iteration's reads complete
    *reinterpret_cast<uint4*>(XhB + st0) = make_uint4(xh[0], xh[1], xh[2], xh[3]);
    *reinterpret_cast<uint4*>(XhB + st1) = make_uint4(xh[4], xh[5], xh[6], xh[7]);
    *reinterpret_cast<uint4*>(XlB + st0) = make_uint4(xl[0], xl[1], xl[2], xl[3]);
    *reinterpret_cast<uint4*>(XlB + st1) = make_uint4(xl[4], xl[5], xl[6], xl[7]);
    *reinterpret_cast<uint4*>(WhB + st0) = make_uint4(wh[0], wh[1], wh[2], wh[3]);
    *reinterpret_cast<uint4*>(WhB + st1) = make_uint4(wh[4], wh[5], wh[6], wh[7]);
    *reinterpret_cast<uint4*>(WlB + st0) = make_uint4(wl[0], wl[1], wl[2], wl[3]);
    *reinterpret_cast<uint4*>(WlB + st1) = make_uint4(wl[4], wl[5], wl[6], wl[7]);
    __syncthreads();  // tile visible

    bf16x8 ah[2], al[2];
#pragma unroll
    for (int mt = 0; mt < 2; ++mt) {
      ah[mt] = *reinterpret_cast<const bf16x8*>(XhB + aOff[mt]);
      al[mt] = *reinterpret_cast<const bf16x8*>(XlB + aOff[mt]);
    }
#pragma unroll
    for (int nt = 0; nt < 8; ++nt) {
      bf16x8 bh = *reinterpret_cast<const bf16x8*>(WhB + bOff[nt]);
      bf16x8 bl = *reinterpret_cast<const bf16x8*>(WlB + bOff[nt]);
#pragma unroll
      for (int mt = 0; mt < 2; ++mt) {
        acc[mt][nt] = __builtin_amdgcn_mfma_f32_16x16x32_bf16(ah[mt], bh, acc[mt][nt], 0, 0, 0);
        acc[mt][nt] = __builtin_amdgcn_mfma_f32_16x16x32_bf16(ah[mt], bl, acc[mt][nt], 0, 0, 0);
        acc[mt][nt] = __builtin_amdgcn_mfma_f32_16x16x32_bf16(al[mt], bh, acc[mt][nt], 0, 0, 0);
      }
    }
  }

  // ---- epilogue: bias + dropout mask + store ----
  float bias[8];
#pragma unroll
  for (int nt = 0; nt < 8; ++nt) bias[nt] = bp[nt * 16 + lx];

#pragma unroll
  for (int s = 0; s < 8; ++s) {
    const int mt = s >> 2, reg = s & 3;
    const int row = row0 + wv * 32 + mt * 16 + lq * 4 + reg;
    if (row < N) {
      float* orow = op + (size_t)row * 128 + lx;
#pragma unroll
      for (int nt = 0; nt < 8; ++nt) {
        float y = acc[mt][nt][reg] + bias[nt];
        bool kp = (keep64 >> (s * 8 + nt)) & 1ULL;
        orow[nt * 16] = kp ? y * 1.25f : 0.0f;
      }
    }
  }
}

extern "C" void kernel_launch(void* const* d_in, const int* in_sizes, int n_in,
                              void* d_out, int out_size, void* d_ws, size_t ws_size,
                              hipStream_t stream) {
  static const int NS[NTYPES] = {100000, 75000, 62500, 50000, 37500, 30000, 25000, 20000};
  static const int CS[NTYPES] = {128, 256, 64, 128, 192, 96, 160, 128};

  KParams P;
  int blk = 0;
  size_t ooff = 0;
  for (int t = 0; t < NTYPES; ++t) {
    P.t[t].x = (const float*)d_in[3 * t + 0];
    P.t[t].W = (const float*)d_in[3 * t + 1];
    P.t[t].b = (const float*)d_in[3 * t + 2];
    P.t[t].out = (float*)d_out + ooff;
    P.t[t].N = NS[t];
    P.t[t].C = CS[t];
    P.t[t].blk_start = blk;
    unsigned o0, o1;
    tf2x32(0u, 42u, 0u, (unsigned)t, o0, o1);  // fold_in(key(42), t)
    P.t[t].k0 = o0;
    P.t[t].k1 = o1;
    blk += (NS[t] + BM - 1) / BM;
    ooff += (size_t)NS[t] * OUT_CH;
  }

  hipLaunchKernelGGL(hetero_mfma, dim3(blk), dim3(THREADS), 0, stream, P);
}